// Round 11
// baseline (576.908 us; speedup 1.0000x reference)
//
#include <hip/hip_runtime.h>
#include <cstdint>

#define F0 100
#define FH 128
#define FO 64
#define PD 4  // counter padding (ints) to spread atomic lines
#define BN_EPS 1e-5f

typedef unsigned short ushort_t;
typedef unsigned int uint_t;

static inline int ceil_div(long long a, long long b) { return (int)((a + b - 1) / b); }

// ---- bf16 helpers (fp32 math everywhere; bf16 is storage only) ----
__device__ __forceinline__ float bf_lo(uint_t w) { return __uint_as_float(w << 16); }
__device__ __forceinline__ float bf_hi(uint_t w) { return __uint_as_float(w & 0xffff0000u); }
__device__ __forceinline__ uint_t f2bf(float f) {  // RNE
  uint_t u = __float_as_uint(f);
  return (u + 0x7fffu + ((u >> 16) & 1u)) >> 16;
}
__device__ __forceinline__ uint_t pack2(float a, float b) {
  return f2bf(a) | (f2bf(b) << 16);
}

// ---------------- GEMM body: out[n x F] = A[n x K] @ W[K x F] (+bias, opt BN+relu on A) ----

template <int K, int F, int TM, int BK, bool BN_A, bool A_BF16, bool OUT_BF16>
__device__ __forceinline__ void gemm2_body(int bid, const void* __restrict__ A_,
                                           const float* __restrict__ W,
                                           const float* __restrict__ bias,
                                           const float* __restrict__ scA,
                                           const float* __restrict__ shA,
                                           void* __restrict__ out_, int n) {
  constexpr int NCG = F / 4;
  constexpr int NRG = 256 / NCG;
  constexpr int BR = NRG * TM;
  constexpr int F4 = F / 4;

  __shared__ float sW[BK][F];
  __shared__ float sA[BR][BK];

  const int tid = threadIdx.x;
  const int cg = tid % NCG;
  const int rg = tid / NCG;
  const int row0 = bid * BR;

  float4 acc[TM];
#pragma unroll
  for (int t = 0; t < TM; ++t) acc[t] = make_float4(0.f, 0.f, 0.f, 0.f);

  const float4* W4 = (const float4*)W;
  const float4 z4 = make_float4(0.f, 0.f, 0.f, 0.f);

  for (int k0 = 0; k0 < K; k0 += BK) {
    for (int i = tid; i < BK * F4; i += 256) {
      int kk = i / F4, f4 = i % F4;
      int gk = k0 + kk;
      ((float4*)&sW[kk][0])[f4] = (gk < K) ? W4[(size_t)gk * F4 + f4] : z4;
    }
    for (int i = tid; i < BR * (BK / 4); i += 256) {
      int r = i / (BK / 4), k4 = i % (BK / 4);
      int gr = row0 + r;
      int gk = k0 + k4 * 4;
      float4 av = z4;
      if (gr < n && gk + 3 < K) {
        if (A_BF16) {
          uint2 u = ((const uint2*)A_)[(size_t)gr * (K / 4) + (gk >> 2)];
          av.x = bf_lo(u.x); av.y = bf_hi(u.x);
          av.z = bf_lo(u.y); av.w = bf_hi(u.y);
        } else {
          av = ((const float4*)A_)[(size_t)gr * (K / 4) + (gk >> 2)];
        }
        if (BN_A) {
          float4 sc = ((const float4*)scA)[gk >> 2];
          float4 sh = ((const float4*)shA)[gk >> 2];
          av.x = fmaxf(fmaf(av.x, sc.x, sh.x), 0.f);
          av.y = fmaxf(fmaf(av.y, sc.y, sh.y), 0.f);
          av.z = fmaxf(fmaf(av.z, sc.z, sh.z), 0.f);
          av.w = fmaxf(fmaf(av.w, sc.w, sh.w), 0.f);
        }
      }
      ((float4*)&sA[r][0])[k4] = av;
    }
    __syncthreads();
#pragma unroll 4
    for (int kk = 0; kk < BK; ++kk) {
      float4 w = ((const float4*)&sW[kk][0])[cg];
#pragma unroll
      for (int t = 0; t < TM; ++t) {
        float a = sA[rg * TM + t][kk];
        acc[t].x = fmaf(a, w.x, acc[t].x);
        acc[t].y = fmaf(a, w.y, acc[t].y);
        acc[t].z = fmaf(a, w.z, acc[t].z);
        acc[t].w = fmaf(a, w.w, acc[t].w);
      }
    }
    __syncthreads();
  }

  float4 bb = bias ? ((const float4*)bias)[cg] : z4;
#pragma unroll
  for (int t = 0; t < TM; ++t) {
    int gr = row0 + rg * TM + t;
    if (gr < n) {
      float4 v = acc[t];
      v.x += bb.x; v.y += bb.y; v.z += bb.z; v.w += bb.w;
      if (OUT_BF16) {
        ((uint2*)out_)[(size_t)gr * F4 + cg] = make_uint2(pack2(v.x, v.y), pack2(v.z, v.w));
      } else {
        ((float4*)out_)[(size_t)gr * F4 + cg] = v;
      }
    }
  }
}

template <int K, int F, int TM, int BK, bool BN_A, bool A_BF16, bool OUT_BF16>
__global__ __launch_bounds__(256) void gemm2_kernel(const void* __restrict__ A,
                                                    const float* __restrict__ W,
                                                    const float* __restrict__ bias,
                                                    const float* __restrict__ scA,
                                                    const float* __restrict__ shA,
                                                    void* __restrict__ out, int n) {
  gemm2_body<K, F, TM, BK, BN_A, A_BF16, OUT_BF16>(blockIdx.x, A, W, bias, scA, shA, out, n);
}

// ---------------- fused: gemm0 (x@W0 -> bufA bf16, BK=16) || padded histogram ----------------

__global__ __launch_bounds__(256) void fused_gemm_hist_kernel(
    const float* __restrict__ A, const float* __restrict__ W, void* __restrict__ out, int n,
    int GB, const int* __restrict__ row, const int* __restrict__ col,
    int* __restrict__ degr_p, int* __restrict__ degc_p, int* __restrict__ posw, int E) {
  int bid = blockIdx.x;
  int r5 = bid % 5;
  int g = bid / 5;
  if (r5 == 0 && g < GB) {
    gemm2_body<F0, FH, 8, 16, false, false, true>(g, A, W, nullptr, nullptr, nullptr, out, n);
    return;
  }
  int h = (r5 == 0) ? (bid - GB) : (bid - (g + 1));
  int e = h * 256 + threadIdx.x;
  if (e >= E) return;
  atomicAdd(&degr_p[(size_t)row[e] * PD], 1);
  posw[e] = atomicAdd(&degc_p[(size_t)col[e] * PD], 1);
}

// ---------------- scan: dinv + block scan of degc + fused partials (last-block-done) ------

__global__ __launch_bounds__(256) void scan_fused_kernel(const int* __restrict__ degr_p,
                                                         const int* __restrict__ degc_p,
                                                         float* __restrict__ dinv,
                                                         int* __restrict__ startp,
                                                         int* __restrict__ bsums, int n,
                                                         int* __restrict__ ctr) {
  __shared__ int s[256];
  const int tid = threadIdx.x;
  int i = blockIdx.x * 256 + tid;
  int dc = 0;
  if (i < n) {
    int dr = degr_p[(size_t)i * PD];
    dc = degc_p[(size_t)i * PD];
    dinv[i] = (dr > 0) ? rsqrtf((float)dr) : 0.0f;
  }
  s[tid] = dc;
  __syncthreads();
  for (int off = 1; off < 256; off <<= 1) {
    int t = 0;
    if (tid >= off) t = s[tid - off];
    __syncthreads();
    if (tid >= off) s[tid] += t;
    __syncthreads();
  }
  if (i < n) startp[i] = s[tid] - dc;
  if (tid == 255) bsums[blockIdx.x] = s[255];
  __threadfence();
  __syncthreads();
  __shared__ int lastFlag;
  if (tid == 0) lastFlag = (atomicAdd(ctr, 1) == (int)gridDim.x - 1) ? 1 : 0;
  __syncthreads();
  if (!lastFlag) return;
  int nb = (int)gridDim.x;
  int v = (tid < nb) ? atomicAdd(&bsums[tid], 0) : 0;  // coherent re-read
  s[tid] = v;
  __syncthreads();
  for (int off = 1; off < 256; off <<= 1) {
    int t = 0;
    if (tid >= off) t = s[tid - off];
    __syncthreads();
    if (tid >= off) s[tid] += t;
    __syncthreads();
  }
  if (tid < nb) bsums[tid] = s[tid] - v;  // exclusive
}

// ---------------- atomic-free scatter of packed (src, coef) into dst-bucket order --------

__global__ __launch_bounds__(256) void csr_scatter2_kernel(const int* __restrict__ row,
                                                           const int* __restrict__ col,
                                                           const float* __restrict__ ew,
                                                           const float* __restrict__ dinv,
                                                           const int* __restrict__ startp,
                                                           const int* __restrict__ bsums,
                                                           const int* __restrict__ posw,
                                                           int2* __restrict__ ep, int E) {
  int e = blockIdx.x * blockDim.x + threadIdx.x;
  if (e >= E) return;
  int r = row[e], c = col[e];
  int pos = startp[c] + bsums[c >> 8] + posw[e];
  float coef = dinv[r] * ew[e] * dinv[c];
  ep[pos] = make_int2(r, __float_as_int(coef));
}

// ---------------- conv gather core (F=128 input, bf16, optional BN+relu on loads) --------

template <bool DO_BN>
__device__ __forceinline__ void conv_accum_128(const ushort_t* __restrict__ x, int s0, int d,
                                               int q, const int2* __restrict__ ep,
                                               const float* __restrict__ sc,
                                               const float* __restrict__ sh,
                                               float* __restrict__ acc) {
  constexpr int G2 = FH / 8;
  constexpr int TPD = 8;
  const uint4* x4 = (const uint4*)x;
#pragma unroll
  for (int j = 0; j < 16; ++j) acc[j] = 0.f;
  for (int k = 0; k < d; ++k) {
    int2 e = ep[s0 + k];
    float c = __int_as_float(e.y);
    const uint4* xp = x4 + (size_t)e.x * G2 + q;
    uint4 v0 = xp[0];
    uint4 v1 = xp[TPD];
    uint_t vv[8] = {v0.x, v0.y, v0.z, v0.w, v1.x, v1.y, v1.z, v1.w};
#pragma unroll
    for (int hh = 0; hh < 8; ++hh) {
      float f0 = bf_lo(vv[hh]);
      float f1 = bf_hi(vv[hh]);
      if (DO_BN) {
        f0 = fmaxf(fmaf(f0, sc[2 * hh], sh[2 * hh]), 0.f);
        f1 = fmaxf(fmaf(f1, sc[2 * hh + 1], sh[2 * hh + 1]), 0.f);
      }
      acc[2 * hh] = fmaf(c, f0, acc[2 * hh]);
      acc[2 * hh + 1] = fmaf(c, f1, acc[2 * hh + 1]);
    }
  }
}

// ---------------- conv0 + fused BN0 stats + finalize ----------------
// 64 dsts/block (2 chunks of 32). Thread (dl,q) owns features {8q..8q+7, 64+8q..64+8q+7}.

__global__ __launch_bounds__(256) void conv0_stats_kernel(
    const ushort_t* __restrict__ x, const int* __restrict__ startp,
    const int* __restrict__ bsums, const int* __restrict__ degc_p,
    const int2* __restrict__ ep, const float* __restrict__ bias,
    ushort_t* __restrict__ out, int n, const float* __restrict__ g,
    const float* __restrict__ be, float* __restrict__ sum, float* __restrict__ sumsq,
    float* __restrict__ scale, float* __restrict__ shift, int* __restrict__ ctr) {
  const int tid = threadIdx.x;
  const int dl = tid / 8;
  const int q = tid % 8;

  float s[16], s2[16];
#pragma unroll
  for (int j = 0; j < 16; ++j) { s[j] = 0.f; s2[j] = 0.f; }

  for (int c = 0; c < 2; ++c) {
    int dst = blockIdx.x * 64 + c * 32 + dl;
    if (dst >= n) continue;
    int s0 = startp[dst] + bsums[dst >> 8];
    int d = degc_p[(size_t)dst * PD];
    float acc[16];
    conv_accum_128<false>(x, s0, d, q, ep, nullptr, nullptr, acc);
#pragma unroll
    for (int ch = 0; ch < 2; ++ch) {
#pragma unroll
      for (int j = 0; j < 8; ++j) {
        int f = ch * 64 + 8 * q + j;
        float v = acc[ch * 8 + j] + bias[f];
        acc[ch * 8 + j] = v;
        s[ch * 8 + j] += v;
        s2[ch * 8 + j] += v * v;
      }
    }
    uint4* o4 = (uint4*)out;
    size_t base = (size_t)dst * (FH / 8);
    o4[base + q] = make_uint4(pack2(acc[0], acc[1]), pack2(acc[2], acc[3]),
                              pack2(acc[4], acc[5]), pack2(acc[6], acc[7]));
    o4[base + q + 8] = make_uint4(pack2(acc[8], acc[9]), pack2(acc[10], acc[11]),
                                  pack2(acc[12], acc[13]), pack2(acc[14], acc[15]));
  }

  __shared__ float red[32][8][16];  // 16 KB
  // pass 1: sums
#pragma unroll
  for (int j = 0; j < 16; ++j) red[dl][q][j] = s[j];
  __syncthreads();
  for (int off = 16; off >= 1; off >>= 1) {
    if (dl < off) {
#pragma unroll
      for (int j = 0; j < 16; ++j) red[dl][q][j] += red[dl + off][q][j];
    }
    __syncthreads();
  }
  if (dl == 0) {
#pragma unroll
    for (int j = 0; j < 16; ++j) {
      int f = (j < 8) ? (8 * q + j) : (64 + 8 * q + (j - 8));
      unsafeAtomicAdd(&sum[f], red[0][q][j]);
    }
  }
  __syncthreads();
  // pass 2: sumsq
#pragma unroll
  for (int j = 0; j < 16; ++j) red[dl][q][j] = s2[j];
  __syncthreads();
  for (int off = 16; off >= 1; off >>= 1) {
    if (dl < off) {
#pragma unroll
      for (int j = 0; j < 16; ++j) red[dl][q][j] += red[dl + off][q][j];
    }
    __syncthreads();
  }
  if (dl == 0) {
#pragma unroll
    for (int j = 0; j < 16; ++j) {
      int f = (j < 8) ? (8 * q + j) : (64 + 8 * q + (j - 8));
      unsafeAtomicAdd(&sumsq[f], red[0][q][j]);
    }
  }
  __threadfence();
  __syncthreads();
  __shared__ int lastFlag;
  if (tid == 0) lastFlag = (atomicAdd(ctr, 1) == (int)gridDim.x - 1) ? 1 : 0;
  __syncthreads();
  if (lastFlag && tid < FH) {
    float S = atomicAdd(&sum[tid], 0.0f);    // coherent re-read
    float S2 = atomicAdd(&sumsq[tid], 0.0f);
    float invN = 1.0f / (float)n;
    float mean = S * invN;
    float var = fmaxf(S2 * invN - mean * mean, 0.0f);
    float sc = g[tid] / sqrtf(var + BN_EPS);
    scale[tid] = sc;
    shift[tid] = be[tid] - mean * sc;
  }
}

// ---------------- conv gather (bf16 in), thread = (dst, q): 2 uint4 chunks ----------------

template <int F, bool DO_BN, bool OUT_F32>
__global__ __launch_bounds__(256) void conv_kernel(const ushort_t* __restrict__ x,
                                                   const int* __restrict__ startp,
                                                   const int* __restrict__ bsums,
                                                   const int* __restrict__ degc_p,
                                                   const int2* __restrict__ ep,
                                                   const float* __restrict__ bias,
                                                   const float* __restrict__ scale,
                                                   const float* __restrict__ shift,
                                                   void* __restrict__ out, int n) {
  constexpr int G2 = F / 8;
  constexpr int TPD = G2 / 2;
  long long tid = (long long)blockIdx.x * 256 + threadIdx.x;
  if (tid >= (long long)n * TPD) return;
  int dst = (int)(tid / TPD);
  int q = (int)(tid % TPD);
  int s0 = startp[dst] + bsums[dst >> 8];
  int d = degc_p[(size_t)dst * PD];
  const uint4* x4 = (const uint4*)x;

  float sc[16], sh[16];
  if (DO_BN) {
#pragma unroll
    for (int ch = 0; ch < 2; ++ch) {
      int g = q + ch * TPD;
#pragma unroll
      for (int j = 0; j < 8; ++j) {
        sc[ch * 8 + j] = scale[g * 8 + j];
        sh[ch * 8 + j] = shift[g * 8 + j];
      }
    }
  }

  float acc[16];
#pragma unroll
  for (int j = 0; j < 16; ++j) acc[j] = 0.f;

  for (int k = 0; k < d; ++k) {
    int2 e = ep[s0 + k];
    float c = __int_as_float(e.y);
    const uint4* xp = x4 + (size_t)e.x * G2 + q;
    uint4 v0 = xp[0];
    uint4 v1 = xp[TPD];
    uint_t vv[8] = {v0.x, v0.y, v0.z, v0.w, v1.x, v1.y, v1.z, v1.w};
#pragma unroll
    for (int hh = 0; hh < 8; ++hh) {
      float f0 = bf_lo(vv[hh]);
      float f1 = bf_hi(vv[hh]);
      if (DO_BN) {
        f0 = fmaxf(fmaf(f0, sc[2 * hh], sh[2 * hh]), 0.f);
        f1 = fmaxf(fmaf(f1, sc[2 * hh + 1], sh[2 * hh + 1]), 0.f);
      }
      acc[2 * hh] = fmaf(c, f0, acc[2 * hh]);
      acc[2 * hh + 1] = fmaf(c, f1, acc[2 * hh + 1]);
    }
  }

  if (bias) {
#pragma unroll
    for (int ch = 0; ch < 2; ++ch) {
      int g = q + ch * TPD;
#pragma unroll
      for (int j = 0; j < 8; ++j) acc[ch * 8 + j] += bias[g * 8 + j];
    }
  }

  if (OUT_F32) {
    float4* o4 = (float4*)out;
    size_t base = (size_t)dst * (F / 4);
    o4[base + 2 * q] = make_float4(acc[0], acc[1], acc[2], acc[3]);
    o4[base + 2 * q + 1] = make_float4(acc[4], acc[5], acc[6], acc[7]);
    o4[base + 2 * (q + TPD)] = make_float4(acc[8], acc[9], acc[10], acc[11]);
    o4[base + 2 * (q + TPD) + 1] = make_float4(acc[12], acc[13], acc[14], acc[15]);
  } else {
    uint4* o4 = (uint4*)out;
    size_t base = (size_t)dst * G2;
    o4[base + q] = make_uint4(pack2(acc[0], acc[1]), pack2(acc[2], acc[3]),
                              pack2(acc[4], acc[5]), pack2(acc[6], acc[7]));
    o4[base + q + TPD] = make_uint4(pack2(acc[8], acc[9]), pack2(acc[10], acc[11]),
                                    pack2(acc[12], acc[13]), pack2(acc[14], acc[15]));
  }
}

// ---------------- gemm1 (K=128, F=128, bf16 A, bf16 out) + fused BN1 stats + finalize ----

__global__ __launch_bounds__(256) void gemm1_stats_kernel(
    const ushort_t* __restrict__ A, const float* __restrict__ W,
    const float* __restrict__ bias, ushort_t* __restrict__ out, int n,
    const float* __restrict__ g, const float* __restrict__ be, float* __restrict__ sum,
    float* __restrict__ sumsq, float* __restrict__ scale, float* __restrict__ shift,
    int* __restrict__ ctr) {
  constexpr int K = FH, F = FH, TM = 8, BK = 32;
  constexpr int NCG = F / 4;     // 32
  constexpr int NRG = 256 / NCG; // 8
  constexpr int BR = NRG * TM;   // 64
  constexpr int F4 = F / 4;

  __shared__ float sW[BK][F];
  __shared__ float sA[BR][BK];
  __shared__ float red[NRG][NCG][4];  // 4 KB

  const int tid = threadIdx.x;
  const int cg = tid % NCG;
  const int rg = tid / NCG;
  const int row0 = blockIdx.x * BR;

  float4 acc[TM];
#pragma unroll
  for (int t = 0; t < TM; ++t) acc[t] = make_float4(0.f, 0.f, 0.f, 0.f);

  const float4* W4 = (const float4*)W;
  const float4 z4 = make_float4(0.f, 0.f, 0.f, 0.f);

  for (int k0 = 0; k0 < K; k0 += BK) {
    for (int i = tid; i < BK * F4; i += 256) {
      int kk = i / F4, f4 = i % F4;
      ((float4*)&sW[kk][0])[f4] = W4[(size_t)(k0 + kk) * F4 + f4];
    }
    for (int i = tid; i < BR * (BK / 4); i += 256) {
      int r = i / (BK / 4), k4 = i % (BK / 4);
      int gr = row0 + r;
      int gk = k0 + k4 * 4;
      float4 av = z4;
      if (gr < n) {
        uint2 u = ((const uint2*)A)[(size_t)gr * (K / 4) + (gk >> 2)];
        av.x = bf_lo(u.x); av.y = bf_hi(u.x);
        av.z = bf_lo(u.y); av.w = bf_hi(u.y);
      }
      ((float4*)&sA[r][0])[k4] = av;
    }
    __syncthreads();
#pragma unroll 4
    for (int kk = 0; kk < BK; ++kk) {
      float4 w = ((const float4*)&sW[kk][0])[cg];
#pragma unroll
      for (int t = 0; t < TM; ++t) {
        float a = sA[rg * TM + t][kk];
        acc[t].x = fmaf(a, w.x, acc[t].x);
        acc[t].y = fmaf(a, w.y, acc[t].y);
        acc[t].z = fmaf(a, w.z, acc[t].z);
        acc[t].w = fmaf(a, w.w, acc[t].w);
      }
    }
    __syncthreads();
  }

  float4 bb = ((const float4*)bias)[cg];
  float4 s = z4, s2 = z4;
#pragma unroll
  for (int t = 0; t < TM; ++t) {
    int gr = row0 + rg * TM + t;
    if (gr < n) {
      float4 v = acc[t];
      v.x += bb.x; v.y += bb.y; v.z += bb.z; v.w += bb.w;
      ((uint2*)out)[(size_t)gr * F4 + cg] = make_uint2(pack2(v.x, v.y), pack2(v.z, v.w));
      s.x += v.x; s.y += v.y; s.z += v.z; s.w += v.w;
      s2.x += v.x * v.x; s2.y += v.y * v.y; s2.z += v.z * v.z; s2.w += v.w * v.w;
    }
  }

  // reduce sums over rg
  red[rg][cg][0] = s.x; red[rg][cg][1] = s.y; red[rg][cg][2] = s.z; red[rg][cg][3] = s.w;
  __syncthreads();
  for (int off = 4; off >= 1; off >>= 1) {
    if (rg < off) {
#pragma unroll
      for (int j = 0; j < 4; ++j) red[rg][cg][j] += red[rg + off][cg][j];
    }
    __syncthreads();
  }
  if (rg == 0) {
#pragma unroll
    for (int j = 0; j < 4; ++j) unsafeAtomicAdd(&sum[cg * 4 + j], red[0][cg][j]);
  }
  __syncthreads();
  red[rg][cg][0] = s2.x; red[rg][cg][1] = s2.y; red[rg][cg][2] = s2.z; red[rg][cg][3] = s2.w;
  __syncthreads();
  for (int off = 4; off >= 1; off >>= 1) {
    if (rg < off) {
#pragma unroll
      for (int j = 0; j < 4; ++j) red[rg][cg][j] += red[rg + off][cg][j];
    }
    __syncthreads();
  }
  if (rg == 0) {
#pragma unroll
    for (int j = 0; j < 4; ++j) unsafeAtomicAdd(&sumsq[cg * 4 + j], red[0][cg][j]);
  }
  __threadfence();
  __syncthreads();
  __shared__ int lastFlag;
  if (tid == 0) lastFlag = (atomicAdd(ctr, 1) == (int)gridDim.x - 1) ? 1 : 0;
  __syncthreads();
  if (lastFlag && tid < FH) {
    float S = atomicAdd(&sum[tid], 0.0f);
    float S2 = atomicAdd(&sumsq[tid], 0.0f);
    float invN = 1.0f / (float)n;
    float mean = S * invN;
    float var = fmaxf(S2 * invN - mean * mean, 0.0f);
    float sc = g[tid] / sqrtf(var + BN_EPS);
    scale[tid] = sc;
    shift[tid] = be[tid] - mean * sc;
  }
}

// ---------------- launch ----------------

extern "C" void kernel_launch(void* const* d_in, const int* in_sizes, int n_in,
                              void* d_out, int out_size, void* d_ws, size_t ws_size,
                              hipStream_t stream) {
  const float* x   = (const float*)d_in[0];
  const int*   ei  = (const int*)d_in[1];
  const float* ew  = (const float*)d_in[2];
  const float* W0  = (const float*)d_in[3];
  const float* b0  = (const float*)d_in[4];
  const float* g0  = (const float*)d_in[5];
  const float* be0 = (const float*)d_in[6];
  const float* W1  = (const float*)d_in[7];
  const float* b1  = (const float*)d_in[8];
  const float* g1  = (const float*)d_in[9];
  const float* be1 = (const float*)d_in[10];
  const float* W2  = (const float*)d_in[11];
  const float* b2  = (const float*)d_in[12];

  const int n = in_sizes[0] / F0;
  const int E = in_sizes[2];
  const int* row = ei;
  const int* col = ei + E;

  // workspace layout
  ushort_t* bufA  = (ushort_t*)d_ws;                    // n*FH bf16 (t0 -> conv1-out -> t2)
  ushort_t* bufB  = bufA + (size_t)n * FH;              // n*FH bf16 (z0 -> z1)
  int2*   ep      = (int2*)(bufB + (size_t)n * FH);     // E int2
  // ---- contiguous zero region: [degc_p | degr_p | sums | ctrs] ----
  int*    degc_p  = (int*)(ep + E);                     // n*PD
  int*    degr_p  = degc_p + (size_t)n * PD;            // n*PD
  float*  sum0    = (float*)(degr_p + (size_t)n * PD);  // 128
  float*  sumsq0  = sum0 + FH;                          // 128
  float*  sum1    = sumsq0 + FH;                        // 128
  float*  sumsq1  = sum1 + FH;                          // 128
  int*    ctr     = (int*)(sumsq1 + FH);                // 3 (scan, stats0, stats1)
  const size_t zero_bytes = (2 * (size_t)n * PD + 4 * FH + 3) * 4;
  // ---- rest ----
  int*    startp  = ctr + 3;                            // n
  float*  dinv    = (float*)(startp + n);               // n
  int*    bsums   = (int*)(dinv + n);                   // 256
  float*  scale0  = (float*)(bsums + 256);              // 128
  float*  shift0  = scale0 + FH;
  float*  scale1  = shift0 + FH;
  float*  shift1  = scale1 + FH;
  // transient: posw aliases bufB (consumed by scatter before bufB first written)
  int*    posw    = (int*)bufB;                         // E ints

  const int nb = ceil_div(n, 256);          // <= 256 required by fused scan
  const int GB = ceil_div(n, 64);           // gemm blocks (BR=64)
  const int HB = ceil_div(E, 256);          // edge blocks
  const int CB0 = ceil_div(n, 64);          // conv0 blocks (64 dst/block)
  const int CB_H = ceil_div((long long)n * (FH / 16), 256);  // conv F=128
  const int CB_O = ceil_div((long long)n * (FO / 16), 256);  // conv F=64

  // 1. zero counters/stats
  (void)hipMemsetAsync(degc_p, 0, zero_bytes, stream);
  // 2. fused {gemm0: t0 = x@W0 -> bufA bf16} || {padded histogram + posw}
  fused_gemm_hist_kernel<<<GB + HB, 256, 0, stream>>>(x, W0, bufA, n, GB, row, col,
                                                      degr_p, degc_p, posw, E);
  // 3. scan (block scans + fused partials via last-block-done)
  scan_fused_kernel<<<nb, 256, 0, stream>>>(degr_p, degc_p, dinv, startp, bsums, n, ctr + 0);
  // 4. scatter
  csr_scatter2_kernel<<<HB, 256, 0, stream>>>(row, col, ew, dinv, startp, bsums, posw, ep, E);
  // 5. z0 = conv(t0) + b0 -> bufB, with fused BN0 stats + finalize
  conv0_stats_kernel<<<CB0, 256, 0, stream>>>(bufA, startp, bsums, degc_p, ep, b0, bufB, n,
                                              g0, be0, sum0, sumsq0, scale0, shift0, ctr + 1);
  // 6. conv(relu(bn0(z0))) -> bufA
  conv_kernel<FH, true, false><<<CB_H, 256, 0, stream>>>(
      bufB, startp, bsums, degc_p, ep, nullptr, scale0, shift0, bufA, n);
  // 7. z1 = bufA @ W1 + b1 -> bufB, with fused BN1 stats + finalize
  gemm1_stats_kernel<<<GB, 256, 0, stream>>>(bufA, W1, b1, bufB, n, g1, be1, sum1, sumsq1,
                                             scale1, shift1, ctr + 2);
  // 8. t2 = relu(bn1(z1)) @ W2 -> bufA (n x 64 bf16), BN+relu fused in staging
  gemm2_kernel<FH, FO, 4, 32, true, true, true><<<GB, 256, 0, stream>>>(
      bufB, W2, nullptr, scale1, shift1, bufA, n);
  // 9. out = conv(t2) + b2 -> d_out (fp32)
  conv_kernel<FO, false, true><<<CB_O, 256, 0, stream>>>(
      bufA, startp, bsums, degc_p, ep, b2, nullptr, nullptr, (float*)d_out, n);
}

// Round 12
// 342.553 us; speedup vs baseline: 1.6841x; 1.6841x over previous
//
#include <hip/hip_runtime.h>
#include <cstdint>

#define F0 100
#define FH 128
#define FO 64
#define PD 4  // counter padding (ints)
#define BN_EPS 1e-5f

typedef unsigned short ushort_t;
typedef unsigned int uint_t;
typedef __attribute__((ext_vector_type(8))) __bf16 bf16x8;
typedef __attribute__((ext_vector_type(4))) float f32x4;

static inline int ceil_div(long long a, long long b) { return (int)((a + b - 1) / b); }

// ---- bf16 helpers (fp32 math everywhere; bf16 is storage only) ----
__device__ __forceinline__ float bf_lo(uint_t w) { return __uint_as_float(w << 16); }
__device__ __forceinline__ float bf_hi(uint_t w) { return __uint_as_float(w & 0xffff0000u); }
__device__ __forceinline__ uint_t f2bf(float f) {  // RNE
  uint_t u = __float_as_uint(f);
  return (u + 0x7fffu + ((u >> 16) & 1u)) >> 16;
}
__device__ __forceinline__ uint_t pack2(float a, float b) {
  return f2bf(a) | (f2bf(b) << 16);
}

// ---------------- GEMM body (vector fp32; used for gemm0 inside hist) ----------------

template <int K, int F, int TM, int BK, bool BN_A, bool A_BF16, bool OUT_BF16>
__device__ __forceinline__ void gemm2_body(int bid, const void* __restrict__ A_,
                                           const float* __restrict__ W,
                                           const float* __restrict__ bias,
                                           const float* __restrict__ scA,
                                           const float* __restrict__ shA,
                                           void* __restrict__ out_, int n) {
  constexpr int NCG = F / 4;
  constexpr int NRG = 256 / NCG;
  constexpr int BR = NRG * TM;
  constexpr int F4 = F / 4;

  __shared__ float sW[BK][F];
  __shared__ float sA[BR][BK];

  const int tid = threadIdx.x;
  const int cg = tid % NCG;
  const int rg = tid / NCG;
  const int row0 = bid * BR;

  float4 acc[TM];
#pragma unroll
  for (int t = 0; t < TM; ++t) acc[t] = make_float4(0.f, 0.f, 0.f, 0.f);

  const float4* W4 = (const float4*)W;
  const float4 z4 = make_float4(0.f, 0.f, 0.f, 0.f);

  for (int k0 = 0; k0 < K; k0 += BK) {
    for (int i = tid; i < BK * F4; i += 256) {
      int kk = i / F4, f4 = i % F4;
      int gk = k0 + kk;
      ((float4*)&sW[kk][0])[f4] = (gk < K) ? W4[(size_t)gk * F4 + f4] : z4;
    }
    for (int i = tid; i < BR * (BK / 4); i += 256) {
      int r = i / (BK / 4), k4 = i % (BK / 4);
      int gr = row0 + r;
      int gk = k0 + k4 * 4;
      float4 av = z4;
      if (gr < n && gk + 3 < K) {
        if (A_BF16) {
          uint2 u = ((const uint2*)A_)[(size_t)gr * (K / 4) + (gk >> 2)];
          av.x = bf_lo(u.x); av.y = bf_hi(u.x);
          av.z = bf_lo(u.y); av.w = bf_hi(u.y);
        } else {
          av = ((const float4*)A_)[(size_t)gr * (K / 4) + (gk >> 2)];
        }
        if (BN_A) {
          float4 sc = ((const float4*)scA)[gk >> 2];
          float4 sh = ((const float4*)shA)[gk >> 2];
          av.x = fmaxf(fmaf(av.x, sc.x, sh.x), 0.f);
          av.y = fmaxf(fmaf(av.y, sc.y, sh.y), 0.f);
          av.z = fmaxf(fmaf(av.z, sc.z, sh.z), 0.f);
          av.w = fmaxf(fmaf(av.w, sc.w, sh.w), 0.f);
        }
      }
      ((float4*)&sA[r][0])[k4] = av;
    }
    __syncthreads();
#pragma unroll 4
    for (int kk = 0; kk < BK; ++kk) {
      float4 w = ((const float4*)&sW[kk][0])[cg];
#pragma unroll
      for (int t = 0; t < TM; ++t) {
        float a = sA[rg * TM + t][kk];
        acc[t].x = fmaf(a, w.x, acc[t].x);
        acc[t].y = fmaf(a, w.y, acc[t].y);
        acc[t].z = fmaf(a, w.z, acc[t].z);
        acc[t].w = fmaf(a, w.w, acc[t].w);
      }
    }
    __syncthreads();
  }

  float4 bb = bias ? ((const float4*)bias)[cg] : z4;
#pragma unroll
  for (int t = 0; t < TM; ++t) {
    int gr = row0 + rg * TM + t;
    if (gr < n) {
      float4 v = acc[t];
      v.x += bb.x; v.y += bb.y; v.z += bb.z; v.w += bb.w;
      if (OUT_BF16) {
        ((uint2*)out_)[(size_t)gr * F4 + cg] = make_uint2(pack2(v.x, v.y), pack2(v.z, v.w));
      } else {
        ((float4*)out_)[(size_t)gr * F4 + cg] = v;
      }
    }
  }
}

// ---------------- MFMA GEMM: out[n x FOUT] bf16 = A[n x 128] bf16 @ W[128 x FOUT] fp32 ----
// 256 thr = 4 waves, 64 rows/block. A-frags load direct from global (aligned uint4).
// W staged once to LDS bf16 in [kq][c][8] chunks (16B-aligned B-frag reads, ~2-way banks).
// mfma_f32_16x16x32_bf16; C/D: col=lane&15, row=(lane>>4)*4+reg (m89-verified).

template <int FOUT, bool BN_A>
__global__ __launch_bounds__(256) void gemm_mfma_kernel(const ushort_t* __restrict__ A,
                                                        const float* __restrict__ W,
                                                        const float* __restrict__ bias,
                                                        const float* __restrict__ scA,
                                                        const float* __restrict__ shA,
                                                        ushort_t* __restrict__ out, int n) {
  constexpr int F4 = FOUT / 4;
  constexpr int NT = FOUT / 16;
  __shared__ ushort_t Wt[16 * FOUT * 8];  // [kq=K/8][c][8 k-elems]

  const int tid = threadIdx.x;
  const float4* W4 = (const float4*)W;
  uint_t* w32 = (uint_t*)Wt;
  for (int idx = tid; idx < 64 * F4; idx += 256) {
    int kp = idx / F4, cq = idx % F4;  // kp = k-pair (2k, 2k+1), cq = col quad
    float4 wa = W4[(size_t)(2 * kp) * F4 + cq];
    float4 wb = W4[(size_t)(2 * kp + 1) * F4 + cq];
    int kq = kp >> 2, e2 = kp & 3;
    int base = (kq * FOUT + cq * 4) * 4 + e2;  // dword index
    w32[base]      = pack2(wa.x, wb.x);
    w32[base + 4]  = pack2(wa.y, wb.y);
    w32[base + 8]  = pack2(wa.z, wb.z);
    w32[base + 12] = pack2(wa.w, wb.w);
  }
  __syncthreads();

  const int l = tid & 63;
  const int wv = tid >> 6;
  const int cc = l & 15;
  const int h = l >> 4;
  const int rowa = blockIdx.x * 64 + wv * 16 + cc;
  const int ra = (rowa < n) ? rowa : (n - 1);

  f32x4 acc[NT];
#pragma unroll
  for (int t = 0; t < NT; ++t) acc[t] = (f32x4)0.f;

#pragma unroll
  for (int ks = 0; ks < 4; ++ks) {
    const int k0 = 32 * ks;
    uint4 av = *(const uint4*)(A + (size_t)ra * FH + k0 + 8 * h);
    if (BN_A) {
      const float4* sc4 = (const float4*)(scA + k0 + 8 * h);
      const float4* sh4 = (const float4*)(shA + k0 + 8 * h);
      float4 sa = sc4[0], sb = sc4[1], ha = sh4[0], hb = sh4[1];
      av.x = pack2(fmaxf(fmaf(bf_lo(av.x), sa.x, ha.x), 0.f),
                   fmaxf(fmaf(bf_hi(av.x), sa.y, ha.y), 0.f));
      av.y = pack2(fmaxf(fmaf(bf_lo(av.y), sa.z, ha.z), 0.f),
                   fmaxf(fmaf(bf_hi(av.y), sa.w, ha.w), 0.f));
      av.z = pack2(fmaxf(fmaf(bf_lo(av.z), sb.x, hb.x), 0.f),
                   fmaxf(fmaf(bf_hi(av.z), sb.y, hb.y), 0.f));
      av.w = pack2(fmaxf(fmaf(bf_lo(av.w), sb.z, hb.z), 0.f),
                   fmaxf(fmaf(bf_hi(av.w), sb.w, hb.w), 0.f));
    }
    bf16x8 afrag = __builtin_bit_cast(bf16x8, av);
    const int kq = ks * 4 + h;
#pragma unroll
    for (int ct = 0; ct < NT; ++ct) {
      int c = ct * 16 + cc;
      uint4 bv = *(const uint4*)(Wt + ((size_t)kq * FOUT + c) * 8);
      bf16x8 bfrag = __builtin_bit_cast(bf16x8, bv);
      acc[ct] = __builtin_amdgcn_mfma_f32_16x16x32_bf16(afrag, bfrag, acc[ct], 0, 0, 0);
    }
  }

  const int rbase = blockIdx.x * 64 + wv * 16 + 4 * h;
#pragma unroll
  for (int ct = 0; ct < NT; ++ct) {
    int c = ct * 16 + cc;
    float bvv = bias ? bias[c] : 0.f;
#pragma unroll
    for (int r = 0; r < 4; ++r) {
      int gr = rbase + r;
      if (gr < n) out[(size_t)gr * FOUT + c] = (ushort_t)f2bf(acc[ct][r] + bvv);
    }
  }
}

// ---------------- fused: gemm0 (x@W0 -> bufA bf16, BK=16) || padded histogram ----------------

__global__ __launch_bounds__(256) void fused_gemm_hist_kernel(
    const float* __restrict__ A, const float* __restrict__ W, void* __restrict__ out, int n,
    int GB, const int* __restrict__ row, const int* __restrict__ col,
    int* __restrict__ degr_p, int* __restrict__ degc_p, int* __restrict__ posw, int E) {
  int bid = blockIdx.x;
  int r5 = bid % 5;
  int g = bid / 5;
  if (r5 == 0 && g < GB) {
    gemm2_body<F0, FH, 8, 16, false, false, true>(g, A, W, nullptr, nullptr, nullptr, out, n);
    return;
  }
  int h = (r5 == 0) ? (bid - GB) : (bid - (g + 1));
  int e = h * 256 + threadIdx.x;
  if (e >= E) return;
  atomicAdd(&degr_p[(size_t)row[e] * PD], 1);
  posw[e] = atomicAdd(&degc_p[(size_t)col[e] * PD], 1);
}

// ---------------- scan: dinv + block scan of degc + fused partials (last-block-done) ------

__global__ __launch_bounds__(256) void scan_fused_kernel(const int* __restrict__ degr_p,
                                                         const int* __restrict__ degc_p,
                                                         float* __restrict__ dinv,
                                                         int* __restrict__ startp,
                                                         int* __restrict__ bsums, int n,
                                                         int* __restrict__ ctr) {
  __shared__ int s[256];
  const int tid = threadIdx.x;
  int i = blockIdx.x * 256 + tid;
  int dc = 0;
  if (i < n) {
    int dr = degr_p[(size_t)i * PD];
    dc = degc_p[(size_t)i * PD];
    dinv[i] = (dr > 0) ? rsqrtf((float)dr) : 0.0f;
  }
  s[tid] = dc;
  __syncthreads();
  for (int off = 1; off < 256; off <<= 1) {
    int t = 0;
    if (tid >= off) t = s[tid - off];
    __syncthreads();
    if (tid >= off) s[tid] += t;
    __syncthreads();
  }
  if (i < n) startp[i] = s[tid] - dc;
  if (tid == 255) bsums[blockIdx.x] = s[255];
  __threadfence();
  __syncthreads();
  __shared__ int lastFlag;
  if (tid == 0) lastFlag = (atomicAdd(ctr, 1) == (int)gridDim.x - 1) ? 1 : 0;
  __syncthreads();
  if (!lastFlag) return;
  int nb = (int)gridDim.x;
  int v = (tid < nb) ? atomicAdd(&bsums[tid], 0) : 0;  // coherent re-read
  s[tid] = v;
  __syncthreads();
  for (int off = 1; off < 256; off <<= 1) {
    int t = 0;
    if (tid >= off) t = s[tid - off];
    __syncthreads();
    if (tid >= off) s[tid] += t;
    __syncthreads();
  }
  if (tid < nb) bsums[tid] = s[tid] - v;  // exclusive
}

// ---------------- atomic-free scatter of packed (src, coef) into dst-bucket order --------

__global__ __launch_bounds__(256) void csr_scatter2_kernel(const int* __restrict__ row,
                                                           const int* __restrict__ col,
                                                           const float* __restrict__ ew,
                                                           const float* __restrict__ dinv,
                                                           const int* __restrict__ startp,
                                                           const int* __restrict__ bsums,
                                                           const int* __restrict__ posw,
                                                           int2* __restrict__ ep, int E) {
  int e = blockIdx.x * blockDim.x + threadIdx.x;
  if (e >= E) return;
  int r = row[e], c = col[e];
  int pos = startp[c] + bsums[c >> 8] + posw[e];
  float coef = dinv[r] * ew[e] * dinv[c];
  ep[pos] = make_int2(r, __float_as_int(coef));
}

// ---------------- conv gather (bf16 in), thread = (dst, q): 2 uint4 chunks ----------------

template <int F, bool DO_BN, bool OUT_F32>
__global__ __launch_bounds__(256) void conv_kernel(const ushort_t* __restrict__ x,
                                                   const int* __restrict__ startp,
                                                   const int* __restrict__ bsums,
                                                   const int* __restrict__ degc_p,
                                                   const int2* __restrict__ ep,
                                                   const float* __restrict__ bias,
                                                   const float* __restrict__ scale,
                                                   const float* __restrict__ shift,
                                                   void* __restrict__ out, int n) {
  constexpr int G2 = F / 8;
  constexpr int TPD = G2 / 2;
  long long tid = (long long)blockIdx.x * 256 + threadIdx.x;
  if (tid >= (long long)n * TPD) return;
  int dst = (int)(tid / TPD);
  int q = (int)(tid % TPD);
  int s0 = startp[dst] + bsums[dst >> 8];
  int d = degc_p[(size_t)dst * PD];
  const uint4* x4 = (const uint4*)x;

  float sc[16], sh[16];
  if (DO_BN) {
#pragma unroll
    for (int ch = 0; ch < 2; ++ch) {
      int g = q + ch * TPD;
#pragma unroll
      for (int j = 0; j < 8; ++j) {
        sc[ch * 8 + j] = scale[g * 8 + j];
        sh[ch * 8 + j] = shift[g * 8 + j];
      }
    }
  }

  float acc[16];
#pragma unroll
  for (int j = 0; j < 16; ++j) acc[j] = 0.f;

  for (int k = 0; k < d; ++k) {
    int2 e = ep[s0 + k];
    float c = __int_as_float(e.y);
    const uint4* xp = x4 + (size_t)e.x * G2 + q;
    uint4 v0 = xp[0];
    uint4 v1 = xp[TPD];
    uint_t vv[8] = {v0.x, v0.y, v0.z, v0.w, v1.x, v1.y, v1.z, v1.w};
#pragma unroll
    for (int hh = 0; hh < 8; ++hh) {
      float f0 = bf_lo(vv[hh]);
      float f1 = bf_hi(vv[hh]);
      if (DO_BN) {
        f0 = fmaxf(fmaf(f0, sc[2 * hh], sh[2 * hh]), 0.f);
        f1 = fmaxf(fmaf(f1, sc[2 * hh + 1], sh[2 * hh + 1]), 0.f);
      }
      acc[2 * hh] = fmaf(c, f0, acc[2 * hh]);
      acc[2 * hh + 1] = fmaf(c, f1, acc[2 * hh + 1]);
    }
  }

  if (bias) {
#pragma unroll
    for (int ch = 0; ch < 2; ++ch) {
      int g = q + ch * TPD;
#pragma unroll
      for (int j = 0; j < 8; ++j) acc[ch * 8 + j] += bias[g * 8 + j];
    }
  }

  if (OUT_F32) {
    float4* o4 = (float4*)out;
    size_t base = (size_t)dst * (F / 4);
    o4[base + 2 * q] = make_float4(acc[0], acc[1], acc[2], acc[3]);
    o4[base + 2 * q + 1] = make_float4(acc[4], acc[5], acc[6], acc[7]);
    o4[base + 2 * (q + TPD)] = make_float4(acc[8], acc[9], acc[10], acc[11]);
    o4[base + 2 * (q + TPD) + 1] = make_float4(acc[12], acc[13], acc[14], acc[15]);
  } else {
    uint4* o4 = (uint4*)out;
    size_t base = (size_t)dst * G2;
    o4[base + q] = make_uint4(pack2(acc[0], acc[1]), pack2(acc[2], acc[3]),
                              pack2(acc[4], acc[5]), pack2(acc[6], acc[7]));
    o4[base + q + TPD] = make_uint4(pack2(acc[8], acc[9]), pack2(acc[10], acc[11]),
                                    pack2(acc[12], acc[13]), pack2(acc[14], acc[15]));
  }
}

// ---------------- fast BN stats: coalesced uint4 reads + LDS reduce + last-block finalize --

__global__ __launch_bounds__(256) void bn_stats_fast_kernel(const ushort_t* __restrict__ z,
                                                            float* __restrict__ sum,
                                                            float* __restrict__ sumsq,
                                                            const float* __restrict__ g,
                                                            const float* __restrict__ be,
                                                            float* __restrict__ scale,
                                                            float* __restrict__ shift,
                                                            int n, int* __restrict__ ctr) {
  const int tid = threadIdx.x;
  const int q = tid & 15;
  const int rg = tid >> 4;
  const uint4* z4 = (const uint4*)z;

  float s[8], s2[8];
#pragma unroll
  for (int j = 0; j < 8; ++j) { s[j] = 0.f; s2[j] = 0.f; }

  for (int r = blockIdx.x * 16 + rg; r < n; r += (int)gridDim.x * 16) {
    uint4 v = z4[(size_t)r * (FH / 8) + q];
    uint_t vv[4] = {v.x, v.y, v.z, v.w};
#pragma unroll
    for (int h = 0; h < 4; ++h) {
      float f0 = bf_lo(vv[h]);
      float f1 = bf_hi(vv[h]);
      s[2 * h] += f0;      s2[2 * h] += f0 * f0;
      s[2 * h + 1] += f1;  s2[2 * h + 1] += f1 * f1;
    }
  }

  __shared__ float red[256][8];
#pragma unroll
  for (int j = 0; j < 8; ++j) red[tid][j] = s[j];
  __syncthreads();
  for (int off = 128; off >= 16; off >>= 1) {
    if (tid < off) {
#pragma unroll
      for (int j = 0; j < 8; ++j) red[tid][j] += red[tid + off][j];
    }
    __syncthreads();
  }
  if (tid < 16) {
#pragma unroll
    for (int j = 0; j < 8; ++j) unsafeAtomicAdd(&sum[8 * tid + j], red[tid][j]);
  }
  __syncthreads();
#pragma unroll
  for (int j = 0; j < 8; ++j) red[tid][j] = s2[j];
  __syncthreads();
  for (int off = 128; off >= 16; off >>= 1) {
    if (tid < off) {
#pragma unroll
      for (int j = 0; j < 8; ++j) red[tid][j] += red[tid + off][j];
    }
    __syncthreads();
  }
  if (tid < 16) {
#pragma unroll
    for (int j = 0; j < 8; ++j) unsafeAtomicAdd(&sumsq[8 * tid + j], red[tid][j]);
  }
  __threadfence();
  __syncthreads();
  __shared__ int lastFlag;
  if (tid == 0) lastFlag = (atomicAdd(ctr, 1) == (int)gridDim.x - 1) ? 1 : 0;
  __syncthreads();
  if (lastFlag && tid < FH) {
    float S = atomicAdd(&sum[tid], 0.0f);
    float S2 = atomicAdd(&sumsq[tid], 0.0f);
    float invN = 1.0f / (float)n;
    float mean = S * invN;
    float var = fmaxf(S2 * invN - mean * mean, 0.0f);
    float sc = g[tid] / sqrtf(var + BN_EPS);
    scale[tid] = sc;
    shift[tid] = be[tid] - mean * sc;
  }
}

// ---------------- launch ----------------

extern "C" void kernel_launch(void* const* d_in, const int* in_sizes, int n_in,
                              void* d_out, int out_size, void* d_ws, size_t ws_size,
                              hipStream_t stream) {
  const float* x   = (const float*)d_in[0];
  const int*   ei  = (const int*)d_in[1];
  const float* ew  = (const float*)d_in[2];
  const float* W0  = (const float*)d_in[3];
  const float* b0  = (const float*)d_in[4];
  const float* g0  = (const float*)d_in[5];
  const float* be0 = (const float*)d_in[6];
  const float* W1  = (const float*)d_in[7];
  const float* b1  = (const float*)d_in[8];
  const float* g1  = (const float*)d_in[9];
  const float* be1 = (const float*)d_in[10];
  const float* W2  = (const float*)d_in[11];
  const float* b2  = (const float*)d_in[12];

  const int n = in_sizes[0] / F0;
  const int E = in_sizes[2];
  const int* row = ei;
  const int* col = ei + E;

  // workspace layout
  ushort_t* bufA  = (ushort_t*)d_ws;                    // n*FH bf16 (t0 -> conv1-out -> t2)
  ushort_t* bufB  = bufA + (size_t)n * FH;              // n*FH bf16 (z0 -> z1)
  int2*   ep      = (int2*)(bufB + (size_t)n * FH);     // E int2
  // ---- contiguous zero region: [degc_p | degr_p | sums | ctrs] ----
  int*    degc_p  = (int*)(ep + E);                     // n*PD
  int*    degr_p  = degc_p + (size_t)n * PD;            // n*PD
  float*  sum0    = (float*)(degr_p + (size_t)n * PD);  // 128
  float*  sumsq0  = sum0 + FH;                          // 128
  float*  sum1    = sumsq0 + FH;                        // 128
  float*  sumsq1  = sum1 + FH;                          // 128
  int*    ctr     = (int*)(sumsq1 + FH);                // 3 (scan, stats0, stats1)
  const size_t zero_bytes = (2 * (size_t)n * PD + 4 * FH + 3) * 4;
  // ---- rest ----
  int*    startp  = ctr + 3;                            // n
  float*  dinv    = (float*)(startp + n);               // n
  int*    bsums   = (int*)(dinv + n);                   // 256
  float*  scale0  = (float*)(bsums + 256);              // 128
  float*  shift0  = scale0 + FH;
  float*  scale1  = shift0 + FH;
  float*  shift1  = scale1 + FH;
  // transient: posw aliases bufB (consumed by scatter before bufB first written)
  int*    posw    = (int*)bufB;                         // E ints

  const int nb = ceil_div(n, 256);          // <= 256 required by fused scan
  const int GB = ceil_div(n, 64);           // gemm0 blocks (BR=64)
  const int HB = ceil_div(E, 256);          // edge blocks
  const int MB = ceil_div(n, 64);           // mfma gemm blocks (64 rows/block)
  const int CB_H = ceil_div((long long)n * (FH / 16), 256);  // conv F=128
  const int CB_O = ceil_div((long long)n * (FO / 16), 256);  // conv F=64

  // 1. zero counters/stats
  (void)hipMemsetAsync(degc_p, 0, zero_bytes, stream);
  // 2. fused {gemm0: t0 = x@W0 -> bufA bf16} || {padded histogram + posw}
  fused_gemm_hist_kernel<<<GB + HB, 256, 0, stream>>>(x, W0, bufA, n, GB, row, col,
                                                      degr_p, degc_p, posw, E);
  // 3. scan (block scans + fused partials via last-block-done)
  scan_fused_kernel<<<nb, 256, 0, stream>>>(degr_p, degc_p, dinv, startp, bsums, n, ctr + 0);
  // 4. scatter
  csr_scatter2_kernel<<<HB, 256, 0, stream>>>(row, col, ew, dinv, startp, bsums, posw, ep, E);
  // 5. z0 = conv(t0) + b0 -> bufB
  conv_kernel<FH, false, false><<<CB_H, 256, 0, stream>>>(
      bufA, startp, bsums, degc_p, ep, b0, nullptr, nullptr, bufB, n);
  // 6. stats0 + finalize -> scale0/shift0
  bn_stats_fast_kernel<<<128, 256, 0, stream>>>(bufB, sum0, sumsq0, g0, be0, scale0, shift0,
                                                n, ctr + 1);
  // 7. conv(relu(bn0(z0))) -> bufA
  conv_kernel<FH, true, false><<<CB_H, 256, 0, stream>>>(
      bufB, startp, bsums, degc_p, ep, nullptr, scale0, shift0, bufA, n);
  // 8. z1 = bufA @ W1 + b1 -> bufB (MFMA)
  gemm_mfma_kernel<FH, false><<<MB, 256, 0, stream>>>(bufA, W1, b1, nullptr, nullptr, bufB, n);
  // 9. stats1 + finalize -> scale1/shift1
  bn_stats_fast_kernel<<<128, 256, 0, stream>>>(bufB, sum1, sumsq1, g1, be1, scale1, shift1,
                                                n, ctr + 2);
  // 10. t2 = relu(bn1(z1)) @ W2 -> bufA (n x 64 bf16, MFMA, BN fused on A-loads)
  gemm_mfma_kernel<FO, true><<<MB, 256, 0, stream>>>(bufB, W2, nullptr, scale1, shift1, bufA, n);
  // 11. out = conv(t2) + b2 -> d_out (fp32)
  conv_kernel<FO, false, true><<<CB_O, 256, 0, stream>>>(
      bufA, startp, bsums, degc_p, ep, b2, nullptr, nullptr, (float*)d_out, n);
}